// Round 10
// baseline (148.637 us; speedup 1.0000x reference)
//
#include <hip/hip_runtime.h>

// LSTM(units=64) over T=5, D_IN=1, then Dense(1, relu).  R10.
// BARRIER-FREE row partitioning: wave w owns batch rows [w*16,w*16+16)
// and computes ALL 256 gate-cols for them -> h(t) is produced and
// consumed by the SAME wave (wave-local LDS round-trip, in-order LDS
// pipe, compiler fences). Zero __syncthreads() in the t-loop.
// Why: R4-R9 ledger = trans-issue floor 58us, wall 93us, 35us of pipe
// bubbles (dep-stalls + 5 inter-wave barriers at ~9 waves/CU; residency
// pin unbreakable by launch_bounds/LDS/block shape). Poly-tanh analyzed:
// needs degree>=13 on [-5,5] (pole at i*pi/2) -> costs what exp2 costs.
// 7 trans/elem is minimal; only the bubbles are winnable.
// Cost of re-partition: U can't be VGPR-resident (16 tiles) -> scaled
// f16 U fragments live in 32KB shared LDS, 8x ds_read_b128 per sub-tile
// per t (LDS pipe, ~34us total BW -- under the 58us trans floor).
// Blocks of 8 independent waves share one B-image: LDS ~55KB -> 2
// blocks/CU; launch_bounds(512,4) caps 128 regs (hand count ~110 with
// W/b in LDS) -> 16 waves/CU vs 8.8.
// Gate math identical to R9 (exp2 + merged rcp, float2 pairs):
//   p=(1+ei)(1+eg), q=(1+ef):  c' = (c*p + q*(1-eg)) * rcp(p*q)
//   h = o*tanh(c') = (1-ec) * rcp((1+eo)(1+ec)),  ec = exp2(-2L*c')
// absmax must stay exactly 1.953e-3.

typedef _Float16 f16x8 __attribute__((ext_vector_type(8)));
typedef float f32x4 __attribute__((ext_vector_type(4)));
typedef float f32x2 __attribute__((ext_vector_type(2)));

#define NTHREADS 512
#define WPB 8            // waves per block
#define MB (WPB * 16)    // 128 batch rows per block
#define HSTR 68          // f16 row stride of per-wave h tile

__device__ __forceinline__ float ex2(float x) { return __builtin_amdgcn_exp2f(x); }
__device__ __forceinline__ float rcp(float x) { return __builtin_amdgcn_rcpf(x); }
__device__ __forceinline__ f32x2 fma2(f32x2 a, f32x2 b, f32x2 c) {
    return __builtin_elementwise_fma(a, b, c);
}

__global__ __launch_bounds__(NTHREADS, 4) void lstm_fused(
    const float* __restrict__ x,   // [B,5,1]
    const float* __restrict__ W,   // [1,256]  gate order i,f,g,o
    const float* __restrict__ U,   // [64,256]
    const float* __restrict__ b,   // [256]
    const float* __restrict__ Wd,  // [64,1]
    const float* __restrict__ bd,  // [1]
    float* __restrict__ out,       // [B,1]
    int B)
{
    // B-fragments: [nt=g*4+sub][kh][lane] ; value: U[kh*32+quad*8+j][g*64+sub*16+l15]*s
    __shared__ f16x8 bfrag[16][2][64];          // 32 KB
    __shared__ _Float16 hb[WPB][16 * HSTR];     // 17 KB, per-wave h tile
    __shared__ float xs[5][MB];                 // 2.5 KB, [t][row]
    __shared__ f32x2 wb[256];                   // 2 KB, {W[n]*s, b[n]*s}
    __shared__ float wds[64];                   // 0.25 KB

    const int tid  = threadIdx.x;
    const int wv   = tid >> 6;
    const int lane = tid & 63;
    const int l15  = lane & 15;
    const int quad = lane >> 4;
    const int row0 = blockIdx.x * MB;

    const float LOG2E = 1.44269504f;
    const float CSC = -2.0f * LOG2E;

    // ---- cooperative staging (one barrier total) ----
    for (int i = tid; i < MB * 5; i += NTHREADS)
        xs[i % 5][i / 5] = x[row0 * 5 + i];
    if (tid < 64) wds[tid] = Wd[tid];
    if (tid < 256) {
        const int g = tid >> 6;
        const float s = (g == 2) ? -2.0f * LOG2E : -LOG2E;
        wb[tid] = (f32x2){W[tid] * s, b[tid] * s};
    }
    for (int e = tid; e < 16 * 2 * 64; e += NTHREADS) {
        const int le = e & 63;
        const int kh = (e >> 6) & 1;
        const int nt = e >> 7;           // g*4+sub
        const int g  = nt >> 2;
        const int n  = g * 64 + (nt & 3) * 16 + (le & 15);
        const int qe = le >> 4;
        const float s = (g == 2) ? -2.0f * LOG2E : -LOG2E;
        f16x8 v;
#pragma unroll
        for (int j = 0; j < 8; ++j)
            v[j] = (_Float16)(U[(kh * 32 + qe * 8 + j) * 256 + n] * s);
        bfrag[nt][kh][le] = v;
    }
    __syncthreads();   // the ONLY block-wide barrier

    _Float16* const hw = &hb[wv][0];

    // cell state: cst[sub][pr] = rows quad*4+2pr+{0,1}, unit sub*16+l15
    f32x2 cst[4][2];
#pragma unroll
    for (int a = 0; a < 4; ++a)
#pragma unroll
        for (int pr = 0; pr < 2; ++pr) cst[a][pr] = (f32x2){0.f, 0.f};

    // ---- t = 0 (h=0, c=0): c = i*g, h = o*tanh(c) ----
    {
        const f32x4 xv = *(const f32x4*)&xs[0][wv * 16 + quad * 4];
#pragma unroll
        for (int sub = 0; sub < 4; ++sub) {
            const f32x2 wbi = wb[0 * 64 + sub * 16 + l15];
            const f32x2 wbg = wb[2 * 64 + sub * 16 + l15];
            const f32x2 wbo = wb[3 * 64 + sub * 16 + l15];
#pragma unroll
            for (int pr = 0; pr < 2; ++pr) {
                const f32x2 xp = {xv[2 * pr], xv[2 * pr + 1]};
                const f32x2 ei = {ex2(__builtin_fmaf(xp.x, wbi.x, wbi.y)),
                                  ex2(__builtin_fmaf(xp.y, wbi.x, wbi.y))};
                const f32x2 eg = {ex2(__builtin_fmaf(xp.x, wbg.x, wbg.y)),
                                  ex2(__builtin_fmaf(xp.y, wbg.x, wbg.y))};
                const f32x2 eo = {ex2(__builtin_fmaf(xp.x, wbo.x, wbo.y)),
                                  ex2(__builtin_fmaf(xp.y, wbo.x, wbo.y))};
                const f32x2 pq = (1.0f + ei) * (1.0f + eg);
                const f32x2 r1 = {rcp(pq.x), rcp(pq.y)};
                const f32x2 cn = (1.0f - eg) * r1;            // i*g
                cst[sub][pr] = cn;
                const f32x2 sc = cn * CSC;
                const f32x2 ec = {ex2(sc.x), ex2(sc.y)};
                const f32x2 dn = (1.0f + eo) * (1.0f + ec);
                const f32x2 r2 = {rcp(dn.x), rcp(dn.y)};
                const f32x2 h2 = (1.0f - ec) * r2;
                const int row = quad * 4 + 2 * pr;
                const int col = sub * 16 + l15;
                hw[row * HSTR + col]       = (_Float16)h2.x;
                hw[(row + 1) * HSTR + col] = (_Float16)h2.y;
            }
        }
    }

    // ---- t = 1..4: barrier-free (own-wave h round-trip) ----
#pragma unroll
    for (int t = 1; t < 5; ++t) {
        // order: previous h-writes before this t's A-reads (in-order LDS
        // pipe per wave; fence stops compiler reordering)
        asm volatile("" ::: "memory");
        const f16x8 a0 = *(const f16x8*)&hw[l15 * HSTR + quad * 8];
        const f16x8 a1 = *(const f16x8*)&hw[l15 * HSTR + 32 + quad * 8];
        asm volatile("" ::: "memory");   // A-reads before this t's h-writes
        const f32x4 xv = *(const f32x4*)&xs[t][wv * 16 + quad * 4];
        const f32x2 xlo = {xv[0], xv[1]};
        const f32x2 xhi = {xv[2], xv[3]};
#pragma unroll
        for (int sub = 0; sub < 4; ++sub) {
            f32x4 acc[4];
#pragma unroll
            for (int g = 0; g < 4; ++g) {
                const f32x2 wv2 = wb[g * 64 + sub * 16 + l15];
                const f32x2 wg = {wv2.x, wv2.x};
                const f32x2 bg = {wv2.y, wv2.y};
                const f32x2 zlo = fma2(xlo, wg, bg);
                const f32x2 zhi = fma2(xhi, wg, bg);
                f32x4 z = {zlo.x, zlo.y, zhi.x, zhi.y};
                z = __builtin_amdgcn_mfma_f32_16x16x32_f16(a0, bfrag[g * 4 + sub][0][lane], z, 0, 0, 0);
                z = __builtin_amdgcn_mfma_f32_16x16x32_f16(a1, bfrag[g * 4 + sub][1][lane], z, 0, 0, 0);
                acc[g] = z;
            }
#pragma unroll
            for (int pr = 0; pr < 2; ++pr) {
                const f32x2 ei = {ex2(acc[0][2 * pr]), ex2(acc[0][2 * pr + 1])};
                const f32x2 ef = {ex2(acc[1][2 * pr]), ex2(acc[1][2 * pr + 1])};
                const f32x2 eg = {ex2(acc[2][2 * pr]), ex2(acc[2][2 * pr + 1])};
                const f32x2 eo = {ex2(acc[3][2 * pr]), ex2(acc[3][2 * pr + 1])};
                const f32x2 p  = (1.0f + ei) * (1.0f + eg);
                const f32x2 q  = 1.0f + ef;
                const f32x2 num = fma2(cst[sub][pr], p, q * (1.0f - eg));
                const f32x2 pq  = p * q;
                const f32x2 ipq = {rcp(pq.x), rcp(pq.y)};
                const f32x2 cn  = num * ipq;
                cst[sub][pr] = cn;
                const f32x2 sc = cn * CSC;
                const f32x2 ec = {ex2(sc.x), ex2(sc.y)};
                const f32x2 dn = (1.0f + eo) * (1.0f + ec);
                const f32x2 r2 = {rcp(dn.x), rcp(dn.y)};
                const f32x2 h2 = (1.0f - ec) * r2;
                const int row = quad * 4 + 2 * pr;
                const int col = sub * 16 + l15;
                hw[row * HSTR + col]       = (_Float16)h2.x;
                hw[(row + 1) * HSTR + col] = (_Float16)h2.y;
            }
        }
    }

    // ---- Dense(1, relu): own-wave data, cross-lane reduce, no barrier ----
    asm volatile("" ::: "memory");
    {
        const f16x8 hv0 = *(const f16x8*)&hw[l15 * HSTR + quad * 16];
        const f16x8 hv1 = *(const f16x8*)&hw[l15 * HSTR + quad * 16 + 8];
        const f32x4 w0 = *(const f32x4*)&wds[quad * 16];
        const f32x4 w1 = *(const f32x4*)&wds[quad * 16 + 4];
        const f32x4 w2 = *(const f32x4*)&wds[quad * 16 + 8];
        const f32x4 w3 = *(const f32x4*)&wds[quad * 16 + 12];
        float s = 0.0f;
#pragma unroll
        for (int j = 0; j < 4; ++j) {
            s = __builtin_fmaf((float)hv0[j],     w0[j], s);
            s = __builtin_fmaf((float)hv0[4 + j], w1[j], s);
            s = __builtin_fmaf((float)hv1[j],     w2[j], s);
            s = __builtin_fmaf((float)hv1[4 + j], w3[j], s);
        }
        s += __shfl_xor(s, 16);
        s += __shfl_xor(s, 32);
        if (quad == 0)
            out[row0 + wv * 16 + l15] = fmaxf(s + bd[0], 0.0f);
    }
}

extern "C" void kernel_launch(void* const* d_in, const int* in_sizes, int n_in,
                              void* d_out, int out_size, void* d_ws, size_t ws_size,
                              hipStream_t stream) {
    const float* x  = (const float*)d_in[0];
    const float* W  = (const float*)d_in[1];
    const float* U  = (const float*)d_in[2];
    const float* b  = (const float*)d_in[3];
    const float* Wd = (const float*)d_in[4];
    const float* bd = (const float*)d_in[5];
    float* out = (float*)d_out;
    const int B = in_sizes[0] / 5;
    const int grid = B / MB;   // 262144/128 = 2048 blocks
    lstm_fused<<<grid, NTHREADS, 0, stream>>>(x, W, U, b, Wd, bd, out, B);
}